// Round 1
// baseline (435.763 us; speedup 1.0000x reference)
//
#include <hip/hip_runtime.h>

// G[u][x] = 0.5 * c_u * cos((2x+1)*u*pi/16),  c_0 = sqrt(0.5), c_u = 1 otherwise.
// scale[u,v]*h[u,x]*h[v,y] == G[u][x]*G[v][y], so the same table serves both
// separable IDCT passes.
__device__ __constant__ float G[64] = {
    0.3535533906f,  0.3535533906f,  0.3535533906f,  0.3535533906f,
    0.3535533906f,  0.3535533906f,  0.3535533906f,  0.3535533906f,

    0.4903926402f,  0.4157348062f,  0.2777851165f,  0.0975451610f,
   -0.0975451610f, -0.2777851165f, -0.4157348062f, -0.4903926402f,

    0.4619397663f,  0.1913417162f, -0.1913417162f, -0.4619397663f,
   -0.4619397663f, -0.1913417162f,  0.1913417162f,  0.4619397663f,

    0.4157348062f, -0.0975451610f, -0.4903926402f, -0.2777851165f,
    0.2777851165f,  0.4903926402f,  0.0975451610f, -0.4157348062f,

    0.3535533906f, -0.3535533906f, -0.3535533906f,  0.3535533906f,
    0.3535533906f, -0.3535533906f, -0.3535533906f,  0.3535533906f,

    0.2777851165f, -0.4903926402f,  0.0975451610f,  0.4157348062f,
   -0.4157348062f, -0.0975451610f,  0.4903926402f, -0.2777851165f,

    0.1913417162f, -0.4619397663f,  0.4619397663f, -0.1913417162f,
   -0.1913417162f,  0.4619397663f, -0.4619397663f,  0.1913417162f,

    0.0975451610f, -0.2777851165f,  0.4157348062f, -0.4903926402f,
    0.4903926402f, -0.4157348062f,  0.2777851165f, -0.0975451610f,
};

// One thread per 8x8 block. gid = b*65536 + h*256 + w, so a wave's 64 lanes
// cover 64 consecutive w -> every per-channel global load is a fully
// coalesced 256 B transaction.
__global__ __launch_bounds__(256) void idct_kernel(
    const float* __restrict__ dct,
    const float* __restrict__ mean_,
    const float* __restrict__ std_,
    float* __restrict__ out)
{
    const int gid = blockIdx.x * 256 + threadIdx.x;
    const int w = gid & 255;
    const int h = (gid >> 8) & 255;
    const int b = gid >> 16;

    // base of this thread's coefficient column: dct[b][c][h][w], c stride 65536
    const float* p = dct + (size_t)b * 64 * 65536 + (size_t)h * 256 + (size_t)w;

    // Pass 1 over u: t[x][v] = sum_u G[u][x] * (raw[u*8+v]*std + mean)
    float t[8][8];
#pragma unroll
    for (int x = 0; x < 8; ++x)
#pragma unroll
        for (int v = 0; v < 8; ++v) t[x][v] = 0.0f;

#pragma unroll
    for (int u = 0; u < 8; ++u) {
#pragma unroll
        for (int v = 0; v < 8; ++v) {
            const int c = u * 8 + v;
            const float raw = p[(size_t)c * 65536];
            const float dv = fmaf(raw, std_[c], mean_[c]);
#pragma unroll
            for (int x = 0; x < 8; ++x)
                t[x][v] = fmaf(G[u * 8 + x], dv, t[x][v]);
        }
    }

    // Pass 2 over v + epilogue (pix+128)/255 folded into one FMA.
    const float inv255 = 1.0f / 255.0f;
    const float off128 = 128.0f / 255.0f;

    // out[b][0][8h+x][8w+y]
    const size_t obase = (size_t)b * (2048u * 2048u) + (size_t)(h * 8) * 2048 + (size_t)(w * 8);

#pragma unroll
    for (int x = 0; x < 8; ++x) {
        float pix[8];
#pragma unroll
        for (int y = 0; y < 8; ++y) {
            float s = 0.0f;
#pragma unroll
            for (int v = 0; v < 8; ++v)
                s = fmaf(G[v * 8 + y], t[x][v], s);
            pix[y] = fmaf(s, inv255, off128);
        }
        float4* o = (float4*)(out + obase + (size_t)x * 2048);
        o[0] = make_float4(pix[0], pix[1], pix[2], pix[3]);
        o[1] = make_float4(pix[4], pix[5], pix[6], pix[7]);
    }
}

extern "C" void kernel_launch(void* const* d_in, const int* in_sizes, int n_in,
                              void* d_out, int out_size, void* d_ws, size_t ws_size,
                              hipStream_t stream) {
    const float* dct  = (const float*)d_in[0];
    const float* mean = (const float*)d_in[1];
    const float* std_ = (const float*)d_in[2];
    float* out = (float*)d_out;

    // 16 * 256 * 256 blocks of 8x8, one thread each -> 1,048,576 threads
    const int total_threads = 16 * 256 * 256;
    const int block = 256;
    const int grid = total_threads / block;  // 4096
    idct_kernel<<<grid, block, 0, stream>>>(dct, mean, std_, out);
}